// Round 1
// 2371.801 us; speedup vs baseline: 1.0993x; 1.0993x over previous
//
#include <hip/hip_runtime.h>
#include <hip/hip_bf16.h>
#include <math.h>

typedef __bf16 v8bf __attribute__((ext_vector_type(8)));
typedef float v4f __attribute__((ext_vector_type(4)));

static constexpr int Bz = 32, Sq = 128, Hd = 768, Lr = 12, NHd = 12, FFd = 3072;
static constexpr int TOK = Bz * Sq;   // 4096 tokens
static constexpr int QKVN = 3 * Hd;   // 2304

__device__ __forceinline__ void gload16(const void* g, void* lds) {
  void* gg = const_cast<void*>(g);
  __builtin_amdgcn_global_load_lds(
      (__attribute__((address_space(1))) void*)gg,
      (__attribute__((address_space(3))) void*)lds, 16, 0, 0);
}

__device__ __forceinline__ float gelu_f(float x) {
  // jax.nn.gelu approximate=True (tanh form)
  float u = 0.7978845608028654f * (x + 0.044715f * x * x * x);
  u = fminf(fmaxf(u, -15.f), 15.f);
  float e = __expf(2.f * u);
  return 0.5f * x * (1.f + (e - 1.f) / (e + 1.f));
}

// ---------------- weight prep: fp32 [K][N] -> bf16 [N][K], batched over z ----
__global__ __launch_bounds__(256) void transpose_cast(
    const float* __restrict__ in, __bf16* __restrict__ out, int K, int N,
    size_t in_zs, size_t out_zs) {
  const float* ib = in + (size_t)blockIdx.z * in_zs;
  __bf16* ob = out + (size_t)blockIdx.z * out_zs;
  __shared__ float tile[32][33];
  const int n0 = blockIdx.x * 32, k0 = blockIdx.y * 32;
  const int tx = threadIdx.x & 31, ty = threadIdx.x >> 5;
#pragma unroll
  for (int i = 0; i < 32; i += 8) tile[ty + i][tx] = ib[(size_t)(k0 + ty + i) * N + n0 + tx];
  __syncthreads();
#pragma unroll
  for (int i = 0; i < 32; i += 8) ob[(size_t)(n0 + ty + i) * K + k0 + tx] = (__bf16)tile[tx][ty + i];
}

__global__ __launch_bounds__(256) void concat_bias(
    const float* __restrict__ bq, const float* __restrict__ bk,
    const float* __restrict__ bv, float* __restrict__ bqkv) {
  const int i = blockIdx.x * 256 + threadIdx.x;
  if (i >= Lr * QKVN) return;
  const int l = i / QKVN, j = i % QKVN;
  float v = (j < Hd) ? bq[l * Hd + j] : (j < 2 * Hd) ? bk[l * Hd + j - Hd] : bv[l * Hd + j - 2 * Hd];
  bqkv[i] = v;
}

// ---------------- LayerNorm helper (row = 768 = 256 threads x 3) -------------
__device__ __forceinline__ void ln_write(float v0, float v1, float v2,
    const float* __restrict__ gs, const float* __restrict__ gb,
    float* __restrict__ xf, __bf16* __restrict__ xb, int t) {
  float sum = v0 + v1 + v2;
  float sq = v0 * v0 + v1 * v1 + v2 * v2;
#pragma unroll
  for (int o = 32; o > 0; o >>= 1) { sum += __shfl_xor(sum, o); sq += __shfl_xor(sq, o); }
  __shared__ float red[8];
  const int w = t >> 6;
  if ((t & 63) == 0) { red[w] = sum; red[4 + w] = sq; }
  __syncthreads();
  sum = red[0] + red[1] + red[2] + red[3];
  sq = red[4] + red[5] + red[6] + red[7];
  const float mu = sum * (1.f / 768.f);
  const float rs = rsqrtf(sq * (1.f / 768.f) - mu * mu + 1e-12f);
  float v[3] = {v0, v1, v2};
#pragma unroll
  for (int i = 0; i < 3; i++) {
    const int c = t + 256 * i;
    const float o = gs[c] * (v[i] - mu) * rs + gb[c];
    xf[c] = o;
    xb[c] = (__bf16)o;
  }
}

__global__ __launch_bounds__(256) void embed_ln(
    const int* __restrict__ idx, const int* __restrict__ typ,
    const float* __restrict__ we, const float* __restrict__ pe, const float* __restrict__ te,
    const float* __restrict__ gs, const float* __restrict__ gb,
    float* __restrict__ xf, __bf16* __restrict__ xb) {
  const int r = blockIdx.x, t = threadIdx.x;
  const int s = r & (Sq - 1);
  const size_t wrow = (size_t)idx[r] * Hd;
  const size_t trow = (size_t)typ[r] * Hd;
  float v[3];
#pragma unroll
  for (int i = 0; i < 3; i++) {
    const int c = t + 256 * i;
    v[i] = we[wrow + c] + pe[(size_t)s * Hd + c] + te[trow + c];
  }
  ln_write(v[0], v[1], v[2], gs, gb, xf + (size_t)r * Hd, xb + (size_t)r * Hd, t);
}

// LN over (split0 + split1 + residual)
__global__ __launch_bounds__(256) void ln_k(
    const float* __restrict__ y0, const float* __restrict__ y1,
    const float* __restrict__ resid,
    const float* __restrict__ gs, const float* __restrict__ gb,
    float* __restrict__ xf, __bf16* __restrict__ xb) {
  const int r = blockIdx.x, t = threadIdx.x;
  float v[3];
#pragma unroll
  for (int i = 0; i < 3; i++) {
    const size_t o = (size_t)r * Hd + t + 256 * i;
    v[i] = y0[o] + y1[o] + resid[o];
  }
  ln_write(v[0], v[1], v[2], gs, gb, xf + (size_t)r * Hd, xb + (size_t)r * Hd, t);
}

// ---------------- GEMM: C[M,N] = A[M,K] * Bt[N,K]^T (+bias, epilogue) --------
// 128x128 tile, BK=64, 4 waves (2x2 of 64x64), mfma_f32_16x16x32_bf16.
// LDS staged via global_load_lds(16B); 8-chunk swizzle (2-way = free).
// XCD-bijective block swizzle for L2 locality (all grids have nwg%8==0).
// grid.z = split-K index: split z handles K-range [z*Klen, (z+1)*Klen).
// MODE 0: bf16 out (+bias); 2: bf16 gelu(+bias); 3: f32 out, bias on z==0 only.
template <int MODE>
__global__ __launch_bounds__(256) void gemm_bt(
    const __bf16* __restrict__ A, int lda, const __bf16* __restrict__ Bt, int ldb,
    const float* __restrict__ bias, void* __restrict__ C0, void* __restrict__ C1,
    int M, int N, int Klen) {
  __shared__ alignas(16) __bf16 As[128 * 64];
  __shared__ alignas(16) __bf16 Bs[128 * 64];
  const int z = blockIdx.z;
  A += (size_t)z * Klen;
  Bt += (size_t)z * Klen;
  void* Cout = (z == 0) ? C0 : C1;
  const int t = threadIdx.x;
  const int lane = t & 63, wave = t >> 6;
  const int wm = wave & 1, wn = wave >> 1;

  // T1: XCD-aware bijective swizzle over the (x,y) grid (x fastest = dispatch order).
  const int nwg = gridDim.x * gridDim.y;
  int orig = blockIdx.y * gridDim.x + blockIdx.x;
  int swz = orig;
  if ((nwg & 7) == 0) swz = (orig & 7) * (nwg >> 3) + (orig >> 3);
  const int bx = swz % gridDim.x, by = swz / gridDim.x;
  const int m0 = by * 128, n0 = bx * 128;

  const v4f vzero = {0.f, 0.f, 0.f, 0.f};
  v4f acc[4][4];
#pragma unroll
  for (int i = 0; i < 4; i++)
#pragma unroll
    for (int j = 0; j < 4; j++) acc[i][j] = vzero;

  // Staging: 128 rows x 64 cols bf16 per matrix per iter (16 KB).
  // Thread t fetches 16B chunk kg of rows (rA + 32*i); wave w's 64 lanes cover
  // rows [8w,8w+8) x 8 chunks = 1024 contiguous LDS bytes (gload_lds linear dest).
  const int rA = t >> 3;                  // 0..31
  const int kg = ((t & 7) - rA) & 7;      // swizzled global 16B-chunk index
  const __bf16* Ag = A + (size_t)(m0 + rA) * lda + kg * 8;
  const __bf16* Bg = Bt + (size_t)(n0 + rA) * ldb + kg * 8;
  char* AsL = (char*)As + wave * 1024;
  char* BsL = (char*)Bs + wave * 1024;
  const int cn = lane & 15, q = lane >> 4;
  const int kiter = Klen >> 6;
  for (int kt = 0; kt < kiter; ++kt) {
    __syncthreads();
#pragma unroll
    for (int i = 0; i < 4; i++) {
      gload16(Ag + (size_t)(32 * i) * lda, AsL + 4096 * i);
      gload16(Bg + (size_t)(32 * i) * ldb, BsL + 4096 * i);
    }
    Ag += 64; Bg += 64;
    __syncthreads();
#pragma unroll
    for (int kk = 0; kk < 2; kk++) {
      v8bf a[4], b[4];
#pragma unroll
      for (int i = 0; i < 4; i++) {
        const int ra = wm * 64 + i * 16 + cn;
        a[i] = *(const v8bf*)&As[ra * 64 + (((kk << 2) + q + ra) & 7) * 8];
        const int rb = wn * 64 + i * 16 + cn;
        b[i] = *(const v8bf*)&Bs[rb * 64 + (((kk << 2) + q + rb) & 7) * 8];
      }
#pragma unroll
      for (int i = 0; i < 4; i++)
#pragma unroll
        for (int j = 0; j < 4; j++)
          acc[i][j] = __builtin_amdgcn_mfma_f32_16x16x32_bf16(a[i], b[j], acc[i][j], 0, 0, 0);
    }
  }
#pragma unroll
  for (int i = 0; i < 4; i++) {
    const int row0 = m0 + wm * 64 + i * 16 + q * 4;
#pragma unroll
    for (int j = 0; j < 4; j++) {
      const int col = n0 + wn * 64 + j * 16 + cn;
      const float bv = (MODE == 3) ? ((z == 0) ? bias[col] : 0.f) : bias[col];
#pragma unroll
      for (int r = 0; r < 4; r++) {
        const size_t off = (size_t)(row0 + r) * N + col;
        float v = acc[i][j][r] + bv;
        if (MODE == 0) {
          ((__bf16*)Cout)[off] = (__bf16)v;
        } else if (MODE == 3) {
          ((float*)Cout)[off] = v;
        } else {
          ((__bf16*)Cout)[off] = (__bf16)gelu_f(v);
        }
      }
    }
  }
}

// ---------------- fused attention: one block per (b, h) ---------------------
__global__ __launch_bounds__(256) void attn_k(
    const __bf16* __restrict__ qkv, const int* __restrict__ mask, __bf16* __restrict__ ctx) {
  const int bh = blockIdx.x;
  const int b = bh / NHd, h = bh % NHd;
  union SmemU {
    struct { __bf16 Q[128][72]; __bf16 K[128][72]; } qk;  // +8 pad vs bank conflicts
    __bf16 P[128][136];
  };
  __shared__ alignas(16) SmemU u;
  __shared__ alignas(16) __bf16 Vt[64][136];              // V transposed [d][s]
  __shared__ float biasS[128];
  const int t = threadIdx.x, lane = t & 63, w = t >> 6;
  const int cn = lane & 15, q = lane >> 4;
  const __bf16* base = qkv + (size_t)b * Sq * QKVN + h * 64;
  for (int i = t; i < 1024; i += 256) {
    const int r = i >> 3, c = (i & 7) << 3;
    *(uint4*)&u.qk.Q[r][c] = *(const uint4*)(base + (size_t)r * QKVN + c);
    *(uint4*)&u.qk.K[r][c] = *(const uint4*)(base + (size_t)r * QKVN + Hd + c);
    union { uint4 u4; ushort us[8]; } tv;
    tv.u4 = *(const uint4*)(base + (size_t)r * QKVN + 2 * Hd + c);
#pragma unroll
    for (int j = 0; j < 8; j++) Vt[c + j][r] = ((const __bf16*)tv.us)[j];
  }
  if (t < 128) biasS[t] = (1.f - (float)mask[b * Sq + t]) * -1e9f;
  __syncthreads();

  // S = Q K^T : wave w owns rows [32w, 32w+32), 2x8 tiles, K=64 (2 steps)
  const v4f vzero = {0.f, 0.f, 0.f, 0.f};
  v4f sc[2][8];
#pragma unroll
  for (int i = 0; i < 2; i++)
#pragma unroll
    for (int j = 0; j < 8; j++) sc[i][j] = vzero;
#pragma unroll
  for (int ks = 0; ks < 2; ks++) {
    v8bf a0 = *(const v8bf*)&u.qk.Q[32 * w + cn][ks * 32 + q * 8];
    v8bf a1 = *(const v8bf*)&u.qk.Q[32 * w + 16 + cn][ks * 32 + q * 8];
#pragma unroll
    for (int nt = 0; nt < 8; nt++) {
      v8bf bk = *(const v8bf*)&u.qk.K[16 * nt + cn][ks * 32 + q * 8];
      sc[0][nt] = __builtin_amdgcn_mfma_f32_16x16x32_bf16(a0, bk, sc[0][nt], 0, 0, 0);
      sc[1][nt] = __builtin_amdgcn_mfma_f32_16x16x32_bf16(a1, bk, sc[1][nt], 0, 0, 0);
    }
  }
  // softmax: row (q*4+rg) lives in the 16 lanes of quarter q -> xor-butterfly<16
#pragma unroll
  for (int mt = 0; mt < 2; mt++)
#pragma unroll
    for (int rg = 0; rg < 4; rg++) {
      float vv[8];
      float mx = -3.0e38f;
#pragma unroll
      for (int nt = 0; nt < 8; nt++) {
        vv[nt] = sc[mt][nt][rg] * 0.125f + biasS[16 * nt + cn];
        mx = fmaxf(mx, vv[nt]);
      }
#pragma unroll
      for (int o = 1; o < 16; o <<= 1) mx = fmaxf(mx, __shfl_xor(mx, o));
      float sum = 0.f;
#pragma unroll
      for (int nt = 0; nt < 8; nt++) { vv[nt] = __expf(vv[nt] - mx); sum += vv[nt]; }
#pragma unroll
      for (int o = 1; o < 16; o <<= 1) sum += __shfl_xor(sum, o);
      const float inv = 1.f / sum;
#pragma unroll
      for (int nt = 0; nt < 8; nt++) sc[mt][nt][rg] = vv[nt] * inv;
    }
  __syncthreads();  // all waves finished reading Q/K; P overlays them
#pragma unroll
  for (int mt = 0; mt < 2; mt++)
#pragma unroll
    for (int nt = 0; nt < 8; nt++)
#pragma unroll
      for (int rg = 0; rg < 4; rg++)
        u.P[32 * w + 16 * mt + q * 4 + rg][16 * nt + cn] = (__bf16)sc[mt][nt][rg];
  __syncthreads();
  // ctx = P V : 2x4 tiles, K=128 (4 steps)
  v4f oc[2][4];
#pragma unroll
  for (int i = 0; i < 2; i++)
#pragma unroll
    for (int j = 0; j < 4; j++) oc[i][j] = vzero;
#pragma unroll
  for (int ks = 0; ks < 4; ks++) {
    v8bf a0 = *(const v8bf*)&u.P[32 * w + cn][ks * 32 + q * 8];
    v8bf a1 = *(const v8bf*)&u.P[32 * w + 16 + cn][ks * 32 + q * 8];
#pragma unroll
    for (int nt = 0; nt < 4; nt++) {
      v8bf bv = *(const v8bf*)&Vt[16 * nt + cn][ks * 32 + q * 8];
      oc[0][nt] = __builtin_amdgcn_mfma_f32_16x16x32_bf16(a0, bv, oc[0][nt], 0, 0, 0);
      oc[1][nt] = __builtin_amdgcn_mfma_f32_16x16x32_bf16(a1, bv, oc[1][nt], 0, 0, 0);
    }
  }
  __bf16* cb = ctx + (size_t)b * Sq * Hd + h * 64;
#pragma unroll
  for (int mt = 0; mt < 2; mt++)
#pragma unroll
    for (int nt = 0; nt < 4; nt++)
#pragma unroll
      for (int rg = 0; rg < 4; rg++)
        cb[(size_t)(32 * w + 16 * mt + q * 4 + rg) * Hd + 16 * nt + cn] = (__bf16)oc[mt][nt][rg];
}

// ---------------- head: logits[b,c] = pooled[b]·u_c + s_c -------------------
// u_c[k] = sum_j d2W[k,j] * we[lab[c], j];  s_c = sum_j d2b[j] * we[lab[c], j]
__global__ __launch_bounds__(256) void headw_k(
    const float* __restrict__ d2W, const float* __restrict__ d2b,
    const int* __restrict__ lab, const float* __restrict__ we,
    float* __restrict__ u, float* __restrict__ s) {
  const int t = threadIdx.x, w = t >> 6, k = blockIdx.x;
  __shared__ float red[12];
  if (k < 768) {
    float dv[3];
#pragma unroll
    for (int i = 0; i < 3; i++) dv[i] = d2W[(size_t)k * 768 + t + 256 * i];
    float acc[3];
#pragma unroll
    for (int c = 0; c < 3; c++) {
      const float* wr = we + (size_t)lab[c] * 768;
      float a = 0.f;
#pragma unroll
      for (int i = 0; i < 3; i++) a += dv[i] * wr[t + 256 * i];
#pragma unroll
      for (int o = 32; o > 0; o >>= 1) a += __shfl_xor(a, o);
      acc[c] = a;
    }
    if ((t & 63) == 0) {
#pragma unroll
      for (int c = 0; c < 3; c++) red[c * 4 + w] = acc[c];
    }
    __syncthreads();
    if (t < 3) u[t * 768 + k] = red[t * 4] + red[t * 4 + 1] + red[t * 4 + 2] + red[t * 4 + 3];
  } else {
    const int c = k - 768;
    const float* wr = we + (size_t)lab[c] * 768;
    float a = 0.f;
#pragma unroll
    for (int i = 0; i < 3; i++) a += d2b[t + 256 * i] * wr[t + 256 * i];
#pragma unroll
    for (int o = 32; o > 0; o >>= 1) a += __shfl_xor(a, o);
    if ((t & 63) == 0) red[w] = a;
    __syncthreads();
    if (t == 0) s[c] = red[0] + red[1] + red[2] + red[3];
  }
}

__global__ __launch_bounds__(256) void pool_logits(
    const float* __restrict__ xf, const int* __restrict__ idx,
    const float* __restrict__ u, const float* __restrict__ s,
    float* __restrict__ out) {
  const int b = blockIdx.x, t = threadIdx.x, w = t >> 6;
  __shared__ float validS[128];
  __shared__ float pooled[768];
  __shared__ float red[12];
  if (t < 128) validS[t] = (idx[b * 128 + t] != 0) ? 1.f : 0.f;
  __syncthreads();
  float cnt = 0.f;
  for (int s2 = 0; s2 < 128; s2++) cnt += validS[s2];
  const float icnt = 1.f / fmaxf(cnt, 1.f);
#pragma unroll
  for (int i = 0; i < 3; i++) {
    const int c = t + 256 * i;
    float acc = 0.f;
    for (int s2 = 0; s2 < 128; s2++) acc += xf[(size_t)(b * 128 + s2) * 768 + c] * validS[s2];
    pooled[c] = acc * icnt;
  }
  __syncthreads();
  for (int c = 0; c < 3; c++) {
    float p = 0.f;
    for (int j = t; j < 768; j += 256) p += pooled[j] * u[c * 768 + j];
#pragma unroll
    for (int o = 32; o > 0; o >>= 1) p += __shfl_xor(p, o);
    if ((t & 63) == 0) red[c * 4 + w] = p;
  }
  __syncthreads();
  if (t < 3) out[b * 3 + t] = red[t * 4] + red[t * 4 + 1] + red[t * 4 + 2] + red[t * 4 + 3] + s[t];
}

extern "C" void kernel_launch(void* const* d_in, const int* in_sizes, int n_in,
                              void* d_out, int out_size, void* d_ws, size_t ws_size,
                              hipStream_t stream) {
  const int* idx = (const int*)d_in[0];
  const int* typ = (const int*)d_in[1];
  const int* msk = (const int*)d_in[2];
  const int* lab = (const int*)d_in[3];
  const float* we = (const float*)d_in[4];
  const float* pe = (const float*)d_in[5];
  const float* te = (const float*)d_in[6];
  const float* elns = (const float*)d_in[7];
  const float* elnb = (const float*)d_in[8];
  const float* Wq = (const float*)d_in[9];
  const float* bq = (const float*)d_in[10];
  const float* Wk = (const float*)d_in[11];
  const float* bk = (const float*)d_in[12];
  const float* Wv = (const float*)d_in[13];
  const float* bv = (const float*)d_in[14];
  const float* Wo = (const float*)d_in[15];
  const float* bo = (const float*)d_in[16];
  const float* l1s = (const float*)d_in[17];
  const float* l1b = (const float*)d_in[18];
  const float* W1 = (const float*)d_in[19];
  const float* b1 = (const float*)d_in[20];
  const float* W2 = (const float*)d_in[21];
  const float* b2 = (const float*)d_in[22];
  const float* l2s = (const float*)d_in[23];
  const float* l2b = (const float*)d_in[24];
  const float* d2W = (const float*)d_in[25];
  const float* d2b = (const float*)d_in[26];

  char* p = (char*)d_ws;
  auto carve = [&](size_t bytes) { char* r = p; p += (bytes + 255) & ~(size_t)255; return r; };
  __bf16* Wqkvt = (__bf16*)carve((size_t)Lr * QKVN * Hd * 2);
  __bf16* Wot   = (__bf16*)carve((size_t)Lr * Hd * Hd * 2);
  __bf16* W1t   = (__bf16*)carve((size_t)Lr * FFd * Hd * 2);
  __bf16* W2t   = (__bf16*)carve((size_t)Lr * Hd * FFd * 2);
  float*  bqkv  = (float*)carve((size_t)Lr * QKVN * 4);
  float*  xf    = (float*)carve((size_t)TOK * Hd * 4);
  __bf16* xb    = (__bf16*)carve((size_t)TOK * Hd * 2);
  __bf16* qkvB  = (__bf16*)carve((size_t)TOK * QKVN * 2);
  __bf16* ctxB  = (__bf16*)carve((size_t)TOK * Hd * 2);
  float*  yf    = (float*)carve((size_t)TOK * Hd * 4);
  __bf16* gB    = (__bf16*)carve((size_t)TOK * FFd * 2);
  float*  uB    = (float*)carve(3 * 768 * 4);
  float*  sB    = (float*)carve(4 * 4);
  float*  yf2   = (float*)qkvB;  // split-1 partials; qkvB is dead post-attn

  dim3 blk(256);
  // weight prep (re-done every launch; ws is re-poisoned by the harness)
  transpose_cast<<<dim3(24, 24, 12), blk, 0, stream>>>(Wq, Wqkvt, Hd, Hd, (size_t)Hd * Hd, (size_t)QKVN * Hd);
  transpose_cast<<<dim3(24, 24, 12), blk, 0, stream>>>(Wk, Wqkvt + (size_t)Hd * Hd, Hd, Hd, (size_t)Hd * Hd, (size_t)QKVN * Hd);
  transpose_cast<<<dim3(24, 24, 12), blk, 0, stream>>>(Wv, Wqkvt + (size_t)2 * Hd * Hd, Hd, Hd, (size_t)Hd * Hd, (size_t)QKVN * Hd);
  transpose_cast<<<dim3(24, 24, 12), blk, 0, stream>>>(Wo, Wot, Hd, Hd, (size_t)Hd * Hd, (size_t)Hd * Hd);
  transpose_cast<<<dim3(96, 24, 12), blk, 0, stream>>>(W1, W1t, Hd, FFd, (size_t)Hd * FFd, (size_t)FFd * Hd);
  transpose_cast<<<dim3(24, 96, 12), blk, 0, stream>>>(W2, W2t, FFd, Hd, (size_t)FFd * Hd, (size_t)Hd * FFd);
  concat_bias<<<dim3((Lr * QKVN + 255) / 256), blk, 0, stream>>>(bq, bk, bv, bqkv);
  headw_k<<<dim3(771), blk, 0, stream>>>(d2W, d2b, lab, we, uB, sB);

  embed_ln<<<dim3(TOK), blk, 0, stream>>>(idx, typ, we, pe, te, elns, elnb, xf, xb);

  for (int l = 0; l < Lr; l++) {
    gemm_bt<0><<<dim3(QKVN / 128, TOK / 128, 1), blk, 0, stream>>>(
        xb, Hd, Wqkvt + (size_t)l * QKVN * Hd, Hd, bqkv + l * QKVN, qkvB, nullptr, TOK, QKVN, Hd);
    attn_k<<<dim3(Bz * NHd), blk, 0, stream>>>(qkvB, msk, ctxB);
    gemm_bt<3><<<dim3(Hd / 128, TOK / 128, 2), blk, 0, stream>>>(
        ctxB, Hd, Wot + (size_t)l * Hd * Hd, Hd, bo + l * Hd, yf, yf2, TOK, Hd, Hd / 2);
    ln_k<<<dim3(TOK), blk, 0, stream>>>(yf, yf2, xf, l1s + l * Hd, l1b + l * Hd, xf, xb);
    gemm_bt<2><<<dim3(FFd / 128, TOK / 128, 1), blk, 0, stream>>>(
        xb, Hd, W1t + (size_t)l * FFd * Hd, Hd, b1 + l * FFd, gB, nullptr, TOK, FFd, Hd);
    gemm_bt<3><<<dim3(Hd / 128, TOK / 128, 2), blk, 0, stream>>>(
        gB, FFd, W2t + (size_t)l * Hd * FFd, FFd, b2 + l * Hd, yf, yf2, TOK, Hd, FFd / 2);
    ln_k<<<dim3(TOK), blk, 0, stream>>>(yf, yf2, xf, l2s + l * Hd, l2b + l * Hd, xf, xb);
  }

  pool_logits<<<dim3(Bz), blk, 0, stream>>>(xf, idx, uB, sB, (float*)d_out);
}

// Round 3
// 2200.823 us; speedup vs baseline: 1.1847x; 1.0777x over previous
//
#include <hip/hip_runtime.h>
#include <hip/hip_bf16.h>
#include <math.h>

typedef __bf16 v8bf __attribute__((ext_vector_type(8)));
typedef float v4f __attribute__((ext_vector_type(4)));

static constexpr int Bz = 32, Sq = 128, Hd = 768, Lr = 12, NHd = 12, FFd = 3072;
static constexpr int TOK = Bz * Sq;   // 4096 tokens
static constexpr int QKVN = 3 * Hd;   // 2304

__device__ __forceinline__ void gload16(const void* g, void* lds) {
  void* gg = const_cast<void*>(g);
  __builtin_amdgcn_global_load_lds(
      (__attribute__((address_space(1))) void*)gg,
      (__attribute__((address_space(3))) void*)lds, 16, 0, 0);
}

__device__ __forceinline__ float gelu_f(float x) {
  // jax.nn.gelu approximate=True (tanh form)
  float u = 0.7978845608028654f * (x + 0.044715f * x * x * x);
  u = fminf(fmaxf(u, -15.f), 15.f);
  float e = __expf(2.f * u);
  return 0.5f * x * (1.f + (e - 1.f) / (e + 1.f));
}

// ---------------- weight prep: fp32 [K][N] -> bf16 [N][K], batched over z ----
__global__ __launch_bounds__(256) void transpose_cast(
    const float* __restrict__ in, __bf16* __restrict__ out, int K, int N,
    size_t in_zs, size_t out_zs) {
  const float* ib = in + (size_t)blockIdx.z * in_zs;
  __bf16* ob = out + (size_t)blockIdx.z * out_zs;
  __shared__ float tile[32][33];
  const int n0 = blockIdx.x * 32, k0 = blockIdx.y * 32;
  const int tx = threadIdx.x & 31, ty = threadIdx.x >> 5;
#pragma unroll
  for (int i = 0; i < 32; i += 8) tile[ty + i][tx] = ib[(size_t)(k0 + ty + i) * N + n0 + tx];
  __syncthreads();
#pragma unroll
  for (int i = 0; i < 32; i += 8) ob[(size_t)(n0 + ty + i) * K + k0 + tx] = (__bf16)tile[tx][ty + i];
}

__global__ __launch_bounds__(256) void concat_bias(
    const float* __restrict__ bq, const float* __restrict__ bk,
    const float* __restrict__ bv, float* __restrict__ bqkv) {
  const int i = blockIdx.x * 256 + threadIdx.x;
  if (i >= Lr * QKVN) return;
  const int l = i / QKVN, j = i % QKVN;
  float v = (j < Hd) ? bq[l * Hd + j] : (j < 2 * Hd) ? bk[l * Hd + j - Hd] : bv[l * Hd + j - 2 * Hd];
  bqkv[i] = v;
}

// ---------------- LayerNorm helper (row = 768 = 256 threads x 3) -------------
__device__ __forceinline__ void ln_write(float v0, float v1, float v2,
    const float* __restrict__ gs, const float* __restrict__ gb,
    float* __restrict__ xf, __bf16* __restrict__ xb, int t) {
  float sum = v0 + v1 + v2;
  float sq = v0 * v0 + v1 * v1 + v2 * v2;
#pragma unroll
  for (int o = 32; o > 0; o >>= 1) { sum += __shfl_xor(sum, o); sq += __shfl_xor(sq, o); }
  __shared__ float red[8];
  const int w = t >> 6;
  if ((t & 63) == 0) { red[w] = sum; red[4 + w] = sq; }
  __syncthreads();
  sum = red[0] + red[1] + red[2] + red[3];
  sq = red[4] + red[5] + red[6] + red[7];
  const float mu = sum * (1.f / 768.f);
  const float rs = rsqrtf(sq * (1.f / 768.f) - mu * mu + 1e-12f);
  float v[3] = {v0, v1, v2};
#pragma unroll
  for (int i = 0; i < 3; i++) {
    const int c = t + 256 * i;
    const float o = gs[c] * (v[i] - mu) * rs + gb[c];
    xf[c] = o;
    xb[c] = (__bf16)o;
  }
}

__global__ __launch_bounds__(256) void embed_ln(
    const int* __restrict__ idx, const int* __restrict__ typ,
    const float* __restrict__ we, const float* __restrict__ pe, const float* __restrict__ te,
    const float* __restrict__ gs, const float* __restrict__ gb,
    float* __restrict__ xf, __bf16* __restrict__ xb) {
  const int r = blockIdx.x, t = threadIdx.x;
  const int s = r & (Sq - 1);
  const size_t wrow = (size_t)idx[r] * Hd;
  const size_t trow = (size_t)typ[r] * Hd;
  float v[3];
#pragma unroll
  for (int i = 0; i < 3; i++) {
    const int c = t + 256 * i;
    v[i] = we[wrow + c] + pe[(size_t)s * Hd + c] + te[trow + c];
  }
  ln_write(v[0], v[1], v[2], gs, gb, xf + (size_t)r * Hd, xb + (size_t)r * Hd, t);
}

// LN over (split0 + split1 + residual)
__global__ __launch_bounds__(256) void ln_k(
    const float* __restrict__ y0, const float* __restrict__ y1,
    const float* __restrict__ resid,
    const float* __restrict__ gs, const float* __restrict__ gb,
    float* __restrict__ xf, __bf16* __restrict__ xb) {
  const int r = blockIdx.x, t = threadIdx.x;
  float v[3];
#pragma unroll
  for (int i = 0; i < 3; i++) {
    const size_t o = (size_t)r * Hd + t + 256 * i;
    v[i] = y0[o] + y1[o] + resid[o];
  }
  ln_write(v[0], v[1], v[2], gs, gb, xf + (size_t)r * Hd, xb + (size_t)r * Hd, t);
}

// ---------------- GEMM: C[M,N] = A[M,K] * Bt[N,K]^T (+bias, epilogue) --------
// 128x128 tile, BK=64, 4 waves (2x2 of 64x64), mfma_f32_16x16x32_bf16.
// 2-phase double-buffered (T3 minimum): STAGE(next) issued BEFORE compute(cur);
// the single __syncthreads per tile drains vmcnt after the MFMA phase has
// covered most of the load latency. Distinct named LDS buffers keep buffer
// selection static (no compiler-inserted early vmcnt waits).
// XCD-bijective block swizzle for L2 locality (all grids have nwg%8==0).
// grid.z = split-K index: split z handles K-range [z*Klen, (z+1)*Klen).
// MODE 0: bf16 out (+bias); 2: bf16 gelu(+bias); 3: f32 out, bias on z==0 only.
template <int MODE>
__global__ __launch_bounds__(256) void gemm_bt(
    const __bf16* __restrict__ A, int lda, const __bf16* __restrict__ Bt, int ldb,
    const float* __restrict__ bias, void* __restrict__ C0, void* __restrict__ C1,
    int M, int N, int Klen) {
  __shared__ alignas(16) __bf16 As0[128 * 64], Bs0[128 * 64];
  __shared__ alignas(16) __bf16 As1[128 * 64], Bs1[128 * 64];
  const int z = blockIdx.z;
  A += (size_t)z * Klen;
  Bt += (size_t)z * Klen;
  void* Cout = (z == 0) ? C0 : C1;
  const int t = threadIdx.x;
  const int lane = t & 63, wave = t >> 6;
  const int wm = wave & 1, wn = wave >> 1;

  // T1: XCD-aware bijective swizzle over the (x,y) grid (x fastest = dispatch order).
  const int nwg = gridDim.x * gridDim.y;
  int orig = blockIdx.y * gridDim.x + blockIdx.x;
  int swz = orig;
  if ((nwg & 7) == 0) swz = (orig & 7) * (nwg >> 3) + (orig >> 3);
  const int bx = swz % gridDim.x, by = swz / gridDim.x;
  const int m0 = by * 128, n0 = bx * 128;

  const v4f vzero = {0.f, 0.f, 0.f, 0.f};
  v4f acc[4][4];
#pragma unroll
  for (int i = 0; i < 4; i++)
#pragma unroll
    for (int j = 0; j < 4; j++) acc[i][j] = vzero;

  // Staging: 128 rows x 64 cols bf16 per matrix per tile (16 KB each of A,B).
  // Thread t fetches 16B chunk kg of rows (rA + 32*i); wave w's 64 lanes cover
  // rows [8w,8w+8) x 8 chunks = 1024 contiguous LDS bytes (gload_lds linear dest).
  const int rA = t >> 3;                  // 0..31
  const int kg = ((t & 7) - rA) & 7;      // swizzled global 16B-chunk index
  const __bf16* Ag = A + (size_t)(m0 + rA) * lda + kg * 8;
  const __bf16* Bg = Bt + (size_t)(n0 + rA) * ldb + kg * 8;
  const int ldsOff = wave * 1024;
  const int cn = lane & 15, q = lane >> 4;

  auto stage = [&](__bf16* AsD, __bf16* BsD, int kt) {
    const __bf16* Ap = Ag + kt * 64;
    const __bf16* Bp = Bg + kt * 64;
    char* AsL = (char*)AsD + ldsOff;
    char* BsL = (char*)BsD + ldsOff;
#pragma unroll
    for (int i = 0; i < 4; i++) {
      gload16(Ap + (size_t)(32 * i) * lda, AsL + 4096 * i);
      gload16(Bp + (size_t)(32 * i) * ldb, BsL + 4096 * i);
    }
  };
  auto compute = [&](const __bf16* AsS, const __bf16* BsS) {
#pragma unroll
    for (int kk = 0; kk < 2; kk++) {
      v8bf a[4], b[4];
#pragma unroll
      for (int i = 0; i < 4; i++) {
        const int ra = wm * 64 + i * 16 + cn;
        a[i] = *(const v8bf*)&AsS[ra * 64 + (((kk << 2) + q + ra) & 7) * 8];
        const int rb = wn * 64 + i * 16 + cn;
        b[i] = *(const v8bf*)&BsS[rb * 64 + (((kk << 2) + q + rb) & 7) * 8];
      }
#pragma unroll
      for (int i = 0; i < 4; i++)
#pragma unroll
        for (int j = 0; j < 4; j++)
          acc[i][j] = __builtin_amdgcn_mfma_f32_16x16x32_bf16(a[i], b[j], acc[i][j], 0, 0, 0);
    }
  };

  const int kiter = Klen >> 6;
  stage(As0, Bs0, 0);
  __syncthreads();
  for (int kt = 0; kt < kiter; kt += 2) {
    if (kt + 1 < kiter) stage(As1, Bs1, kt + 1);
    compute(As0, Bs0);
    __syncthreads();
    if (kt + 1 < kiter) {
      if (kt + 2 < kiter) stage(As0, Bs0, kt + 2);
      compute(As1, Bs1);
      __syncthreads();
    }
  }
#pragma unroll
  for (int i = 0; i < 4; i++) {
    const int row0 = m0 + wm * 64 + i * 16 + q * 4;
#pragma unroll
    for (int j = 0; j < 4; j++) {
      const int col = n0 + wn * 64 + j * 16 + cn;
      const float bv = (MODE == 3) ? ((z == 0) ? bias[col] : 0.f) : bias[col];
#pragma unroll
      for (int r = 0; r < 4; r++) {
        const size_t off = (size_t)(row0 + r) * N + col;
        float v = acc[i][j][r] + bv;
        if (MODE == 0) {
          ((__bf16*)Cout)[off] = (__bf16)v;
        } else if (MODE == 3) {
          ((float*)Cout)[off] = v;
        } else {
          ((__bf16*)Cout)[off] = (__bf16)gelu_f(v);
        }
      }
    }
  }
}

// ---------------- fused attention: one block per (b, h) ---------------------
__global__ __launch_bounds__(256) void attn_k(
    const __bf16* __restrict__ qkv, const int* __restrict__ mask, __bf16* __restrict__ ctx) {
  const int bh = blockIdx.x;
  const int b = bh / NHd, h = bh % NHd;
  union SmemU {
    struct { __bf16 Q[128][72]; __bf16 K[128][72]; } qk;  // +8 pad vs bank conflicts
    __bf16 P[128][136];
  };
  __shared__ alignas(16) SmemU u;
  __shared__ alignas(16) __bf16 Vt[64][136];              // V transposed [d][s]
  __shared__ float biasS[128];
  const int t = threadIdx.x, lane = t & 63, w = t >> 6;
  const int cn = lane & 15, q = lane >> 4;
  const __bf16* base = qkv + (size_t)b * Sq * QKVN + h * 64;
  for (int i = t; i < 1024; i += 256) {
    const int r = i >> 3, c = (i & 7) << 3;
    *(uint4*)&u.qk.Q[r][c] = *(const uint4*)(base + (size_t)r * QKVN + c);
    *(uint4*)&u.qk.K[r][c] = *(const uint4*)(base + (size_t)r * QKVN + Hd + c);
    union { uint4 u4; ushort us[8]; } tv;
    tv.u4 = *(const uint4*)(base + (size_t)r * QKVN + 2 * Hd + c);
#pragma unroll
    for (int j = 0; j < 8; j++) Vt[c + j][r] = ((const __bf16*)tv.us)[j];
  }
  if (t < 128) biasS[t] = (1.f - (float)mask[b * Sq + t]) * -1e9f;
  __syncthreads();

  // S = Q K^T : wave w owns rows [32w, 32w+32), 2x8 tiles, K=64 (2 steps)
  const v4f vzero = {0.f, 0.f, 0.f, 0.f};
  v4f sc[2][8];
#pragma unroll
  for (int i = 0; i < 2; i++)
#pragma unroll
    for (int j = 0; j < 8; j++) sc[i][j] = vzero;
#pragma unroll
  for (int ks = 0; ks < 2; ks++) {
    v8bf a0 = *(const v8bf*)&u.qk.Q[32 * w + cn][ks * 32 + q * 8];
    v8bf a1 = *(const v8bf*)&u.qk.Q[32 * w + 16 + cn][ks * 32 + q * 8];
#pragma unroll
    for (int nt = 0; nt < 8; nt++) {
      v8bf bk = *(const v8bf*)&u.qk.K[16 * nt + cn][ks * 32 + q * 8];
      sc[0][nt] = __builtin_amdgcn_mfma_f32_16x16x32_bf16(a0, bk, sc[0][nt], 0, 0, 0);
      sc[1][nt] = __builtin_amdgcn_mfma_f32_16x16x32_bf16(a1, bk, sc[1][nt], 0, 0, 0);
    }
  }
  // softmax: row (q*4+rg) lives in the 16 lanes of quarter q -> xor-butterfly<16
#pragma unroll
  for (int mt = 0; mt < 2; mt++)
#pragma unroll
    for (int rg = 0; rg < 4; rg++) {
      float vv[8];
      float mx = -3.0e38f;
#pragma unroll
      for (int nt = 0; nt < 8; nt++) {
        vv[nt] = sc[mt][nt][rg] * 0.125f + biasS[16 * nt + cn];
        mx = fmaxf(mx, vv[nt]);
      }
#pragma unroll
      for (int o = 1; o < 16; o <<= 1) mx = fmaxf(mx, __shfl_xor(mx, o));
      float sum = 0.f;
#pragma unroll
      for (int nt = 0; nt < 8; nt++) { vv[nt] = __expf(vv[nt] - mx); sum += vv[nt]; }
#pragma unroll
      for (int o = 1; o < 16; o <<= 1) sum += __shfl_xor(sum, o);
      const float inv = 1.f / sum;
#pragma unroll
      for (int nt = 0; nt < 8; nt++) sc[mt][nt][rg] = vv[nt] * inv;
    }
  __syncthreads();  // all waves finished reading Q/K; P overlays them
#pragma unroll
  for (int mt = 0; mt < 2; mt++)
#pragma unroll
    for (int nt = 0; nt < 8; nt++)
#pragma unroll
      for (int rg = 0; rg < 4; rg++)
        u.P[32 * w + 16 * mt + q * 4 + rg][16 * nt + cn] = (__bf16)sc[mt][nt][rg];
  __syncthreads();
  // ctx = P V : 2x4 tiles, K=128 (4 steps)
  v4f oc[2][4];
#pragma unroll
  for (int i = 0; i < 2; i++)
#pragma unroll
    for (int j = 0; j < 4; j++) oc[i][j] = vzero;
#pragma unroll
  for (int ks = 0; ks < 4; ks++) {
    v8bf a0 = *(const v8bf*)&u.P[32 * w + cn][ks * 32 + q * 8];
    v8bf a1 = *(const v8bf*)&u.P[32 * w + 16 + cn][ks * 32 + q * 8];
#pragma unroll
    for (int nt = 0; nt < 4; nt++) {
      v8bf bv = *(const v8bf*)&Vt[16 * nt + cn][ks * 32 + q * 8];
      oc[0][nt] = __builtin_amdgcn_mfma_f32_16x16x32_bf16(a0, bv, oc[0][nt], 0, 0, 0);
      oc[1][nt] = __builtin_amdgcn_mfma_f32_16x16x32_bf16(a1, bv, oc[1][nt], 0, 0, 0);
    }
  }
  __bf16* cb = ctx + (size_t)b * Sq * Hd + h * 64;
#pragma unroll
  for (int mt = 0; mt < 2; mt++)
#pragma unroll
    for (int nt = 0; nt < 4; nt++)
#pragma unroll
      for (int rg = 0; rg < 4; rg++)
        cb[(size_t)(32 * w + 16 * mt + q * 4 + rg) * Hd + 16 * nt + cn] = (__bf16)oc[mt][nt][rg];
}

// ---------------- head: logits[b,c] = pooled[b]·u_c + s_c -------------------
// u_c[k] = sum_j d2W[k,j] * we[lab[c], j];  s_c = sum_j d2b[j] * we[lab[c], j]
__global__ __launch_bounds__(256) void headw_k(
    const float* __restrict__ d2W, const float* __restrict__ d2b,
    const int* __restrict__ lab, const float* __restrict__ we,
    float* __restrict__ u, float* __restrict__ s) {
  const int t = threadIdx.x, w = t >> 6, k = blockIdx.x;
  __shared__ float red[12];
  if (k < 768) {
    float dv[3];
#pragma unroll
    for (int i = 0; i < 3; i++) dv[i] = d2W[(size_t)k * 768 + t + 256 * i];
    float acc[3];
#pragma unroll
    for (int c = 0; c < 3; c++) {
      const float* wr = we + (size_t)lab[c] * 768;
      float a = 0.f;
#pragma unroll
      for (int i = 0; i < 3; i++) a += dv[i] * wr[t + 256 * i];
#pragma unroll
      for (int o = 32; o > 0; o >>= 1) a += __shfl_xor(a, o);
      acc[c] = a;
    }
    if ((t & 63) == 0) {
#pragma unroll
      for (int c = 0; c < 3; c++) red[c * 4 + w] = acc[c];
    }
    __syncthreads();
    if (t < 3) u[t * 768 + k] = red[t * 4] + red[t * 4 + 1] + red[t * 4 + 2] + red[t * 4 + 3];
  } else {
    const int c = k - 768;
    const float* wr = we + (size_t)lab[c] * 768;
    float a = 0.f;
#pragma unroll
    for (int i = 0; i < 3; i++) a += d2b[t + 256 * i] * wr[t + 256 * i];
#pragma unroll
    for (int o = 32; o > 0; o >>= 1) a += __shfl_xor(a, o);
    if ((t & 63) == 0) red[w] = a;
    __syncthreads();
    if (t == 0) s[c] = red[0] + red[1] + red[2] + red[3];
  }
}

__global__ __launch_bounds__(256) void pool_logits(
    const float* __restrict__ xf, const int* __restrict__ idx,
    const float* __restrict__ u, const float* __restrict__ s,
    float* __restrict__ out) {
  const int b = blockIdx.x, t = threadIdx.x, w = t >> 6;
  __shared__ float validS[128];
  __shared__ float pooled[768];
  __shared__ float red[12];
  if (t < 128) validS[t] = (idx[b * 128 + t] != 0) ? 1.f : 0.f;
  __syncthreads();
  float cnt = 0.f;
  for (int s2 = 0; s2 < 128; s2++) cnt += validS[s2];
  const float icnt = 1.f / fmaxf(cnt, 1.f);
#pragma unroll
  for (int i = 0; i < 3; i++) {
    const int c = t + 256 * i;
    float acc = 0.f;
    for (int s2 = 0; s2 < 128; s2++) acc += xf[(size_t)(b * 128 + s2) * 768 + c] * validS[s2];
    pooled[c] = acc * icnt;
  }
  __syncthreads();
  for (int c = 0; c < 3; c++) {
    float p = 0.f;
    for (int j = t; j < 768; j += 256) p += pooled[j] * u[c * 768 + j];
#pragma unroll
    for (int o = 32; o > 0; o >>= 1) p += __shfl_xor(p, o);
    if ((t & 63) == 0) red[c * 4 + w] = p;
  }
  __syncthreads();
  if (t < 3) out[b * 3 + t] = red[t * 4] + red[t * 4 + 1] + red[t * 4 + 2] + red[t * 4 + 3] + s[t];
}

extern "C" void kernel_launch(void* const* d_in, const int* in_sizes, int n_in,
                              void* d_out, int out_size, void* d_ws, size_t ws_size,
                              hipStream_t stream) {
  const int* idx = (const int*)d_in[0];
  const int* typ = (const int*)d_in[1];
  const int* msk = (const int*)d_in[2];
  const int* lab = (const int*)d_in[3];
  const float* we = (const float*)d_in[4];
  const float* pe = (const float*)d_in[5];
  const float* te = (const float*)d_in[6];
  const float* elns = (const float*)d_in[7];
  const float* elnb = (const float*)d_in[8];
  const float* Wq = (const float*)d_in[9];
  const float* bq = (const float*)d_in[10];
  const float* Wk = (const float*)d_in[11];
  const float* bk = (const float*)d_in[12];
  const float* Wv = (const float*)d_in[13];
  const float* bv = (const float*)d_in[14];
  const float* Wo = (const float*)d_in[15];
  const float* bo = (const float*)d_in[16];
  const float* l1s = (const float*)d_in[17];
  const float* l1b = (const float*)d_in[18];
  const float* W1 = (const float*)d_in[19];
  const float* b1 = (const float*)d_in[20];
  const float* W2 = (const float*)d_in[21];
  const float* b2 = (const float*)d_in[22];
  const float* l2s = (const float*)d_in[23];
  const float* l2b = (const float*)d_in[24];
  const float* d2W = (const float*)d_in[25];
  const float* d2b = (const float*)d_in[26];

  char* p = (char*)d_ws;
  auto carve = [&](size_t bytes) { char* r = p; p += (bytes + 255) & ~(size_t)255; return r; };
  __bf16* Wqkvt = (__bf16*)carve((size_t)Lr * QKVN * Hd * 2);
  __bf16* Wot   = (__bf16*)carve((size_t)Lr * Hd * Hd * 2);
  __bf16* W1t   = (__bf16*)carve((size_t)Lr * FFd * Hd * 2);
  __bf16* W2t   = (__bf16*)carve((size_t)Lr * Hd * FFd * 2);
  float*  bqkv  = (float*)carve((size_t)Lr * QKVN * 4);
  float*  xf    = (float*)carve((size_t)TOK * Hd * 4);
  __bf16* xb    = (__bf16*)carve((size_t)TOK * Hd * 2);
  __bf16* qkvB  = (__bf16*)carve((size_t)TOK * QKVN * 2);
  __bf16* ctxB  = (__bf16*)carve((size_t)TOK * Hd * 2);
  float*  yf    = (float*)carve((size_t)TOK * Hd * 4);
  __bf16* gB    = (__bf16*)carve((size_t)TOK * FFd * 2);
  float*  uB    = (float*)carve(3 * 768 * 4);
  float*  sB    = (float*)carve(4 * 4);
  float*  yf2   = (float*)qkvB;  // split-1 partials; qkvB is dead post-attn

  dim3 blk(256);
  // weight prep (re-done every launch; ws is re-poisoned by the harness)
  transpose_cast<<<dim3(24, 24, 12), blk, 0, stream>>>(Wq, Wqkvt, Hd, Hd, (size_t)Hd * Hd, (size_t)QKVN * Hd);
  transpose_cast<<<dim3(24, 24, 12), blk, 0, stream>>>(Wk, Wqkvt + (size_t)Hd * Hd, Hd, Hd, (size_t)Hd * Hd, (size_t)QKVN * Hd);
  transpose_cast<<<dim3(24, 24, 12), blk, 0, stream>>>(Wv, Wqkvt + (size_t)2 * Hd * Hd, Hd, Hd, (size_t)Hd * Hd, (size_t)QKVN * Hd);
  transpose_cast<<<dim3(24, 24, 12), blk, 0, stream>>>(Wo, Wot, Hd, Hd, (size_t)Hd * Hd, (size_t)Hd * Hd);
  transpose_cast<<<dim3(96, 24, 12), blk, 0, stream>>>(W1, W1t, Hd, FFd, (size_t)Hd * FFd, (size_t)FFd * Hd);
  transpose_cast<<<dim3(24, 96, 12), blk, 0, stream>>>(W2, W2t, FFd, Hd, (size_t)FFd * Hd, (size_t)Hd * FFd);
  concat_bias<<<dim3((Lr * QKVN + 255) / 256), blk, 0, stream>>>(bq, bk, bv, bqkv);
  headw_k<<<dim3(771), blk, 0, stream>>>(d2W, d2b, lab, we, uB, sB);

  embed_ln<<<dim3(TOK), blk, 0, stream>>>(idx, typ, we, pe, te, elns, elnb, xf, xb);

  for (int l = 0; l < Lr; l++) {
    gemm_bt<0><<<dim3(QKVN / 128, TOK / 128, 1), blk, 0, stream>>>(
        xb, Hd, Wqkvt + (size_t)l * QKVN * Hd, Hd, bqkv + l * QKVN, qkvB, nullptr, TOK, QKVN, Hd);
    attn_k<<<dim3(Bz * NHd), blk, 0, stream>>>(qkvB, msk, ctxB);
    gemm_bt<3><<<dim3(Hd / 128, TOK / 128, 2), blk, 0, stream>>>(
        ctxB, Hd, Wot + (size_t)l * Hd * Hd, Hd, bo + l * Hd, yf, yf2, TOK, Hd, Hd / 2);
    ln_k<<<dim3(TOK), blk, 0, stream>>>(yf, yf2, xf, l1s + l * Hd, l1b + l * Hd, xf, xb);
    gemm_bt<2><<<dim3(FFd / 128, TOK / 128, 1), blk, 0, stream>>>(
        xb, Hd, W1t + (size_t)l * FFd * Hd, Hd, b1 + l * FFd, gB, nullptr, TOK, FFd, Hd);
    gemm_bt<3><<<dim3(Hd / 128, TOK / 128, 2), blk, 0, stream>>>(
        gB, FFd, W2t + (size_t)l * Hd * FFd, FFd, b2 + l * Hd, yf, yf2, TOK, Hd, FFd / 2);
    ln_k<<<dim3(TOK), blk, 0, stream>>>(yf, yf2, xf, l2s + l * Hd, l2b + l * Hd, xf, xb);
  }

  pool_logits<<<dim3(Bz), blk, 0, stream>>>(xf, idx, uB, sB, (float*)d_out);
}